// Round 6
// baseline (575.943 us; speedup 1.0000x reference)
//
#include <hip/hip_runtime.h>

#define HH 160
#define WW 160

typedef __attribute__((ext_vector_type(8))) short bf16x8;
typedef __attribute__((ext_vector_type(4))) float f32x4;

static __device__ __forceinline__ unsigned short f32_to_bf16_rne(float f) {
    unsigned u = __float_as_uint(f);
    unsigned r = (u + 0x7FFFu + ((u >> 16) & 1u)) >> 16;
    return (unsigned short)r;
}
static __device__ __forceinline__ float bf16_to_f32(unsigned short h) {
    return __uint_as_float(((unsigned)h) << 16);
}

// ---------------------------------------------------------------------------
// Prep: pack pw_w[2] into MFMA B-fragment layout, bf16 hi/lo split.
// frag = (((b*9+kk)*4 + ct)*2 + kh)*2 + comp ; per frag 64 lanes x 8 u16.
// Element (lane,j): B[k=kh*32+(lane>>4)*8+j][n=ct*16+(lane&15)], W[cp][c]=pw[(c*9+kk)*64+cp]
// ---------------------------------------------------------------------------
__global__ __launch_bounds__(256) void prep_w_kernel(const float* __restrict__ pw0,
                                                     const float* __restrict__ pw1,
                                                     unsigned short* __restrict__ wF) {
    int idx = blockIdx.x * 256 + threadIdx.x;   // 288*64 = 18432
    if (idx >= 18432) return;
    int lane = idx & 63;
    int frag = idx >> 6;
    int comp = frag & 1;
    int kh   = (frag >> 1) & 1;
    int ct   = (frag >> 2) & 3;
    int t    = frag >> 4;             // b*9+kk
    int bb   = t / 9;
    int kk   = t - bb * 9;
    const float* pw = bb ? pw1 : pw0;
    int c = ct * 16 + (lane & 15);
    bf16x8 pack;
    #pragma unroll
    for (int j = 0; j < 8; ++j) {
        int cp = kh * 32 + (lane >> 4) * 8 + j;
        float v = pw[(c * 9 + kk) * 64 + cp];
        unsigned short hb = f32_to_bf16_rne(v);
        if (comp == 0) pack[j] = (short)hb;
        else           pack[j] = (short)f32_to_bf16_rne(v - bf16_to_f32(hb));
    }
    *(bf16x8*)&wF[frag * 512 + lane * 8] = pack;
}

// ---------------------------------------------------------------------------
// Fused kernel. Block = 4 h-rows x 32 w = 128 px, all 64 channels, 4 waves.
// Wave wid owns one row (32 px = 2 M-frags) x all 64 output channels.
// CODE-SIZE-DISCIPLINED: kk is a runtime loop (#pragma unroll 1); only ct (x4)
// unrolls inside -> ~6 KB text (fits I$), all reg-array indices static.
// ---------------------------------------------------------------------------
__global__ __launch_bounds__(256, 4) void fused_kernel(
    const float* __restrict__ y,   const float* __restrict__ x,
    const float* __restrict__ dw0, const float* __restrict__ g0,
    const float* __restrict__ bb0, const float* __restrict__ m0,
    const float* __restrict__ v0,  const float* __restrict__ pwb0,
    const float* __restrict__ dw1, const float* __restrict__ g1,
    const float* __restrict__ bb1, const float* __restrict__ m1,
    const float* __restrict__ v1,  const float* __restrict__ pwb1,
    const float* __restrict__ ng,  const float* __restrict__ nbb,
    const float* __restrict__ nm,  const float* __restrict__ nv,
    const unsigned short* __restrict__ wF, float* __restrict__ out)
{
    __shared__ unsigned short t_hi[128 * 64];   // [px][8 slots], 128B rows, XOR swizzle
    __shared__ unsigned short t_lo[128 * 64];
    __shared__ float dwl[2 * 576];
    __shared__ float scb[2 * 64], shb[2 * 64], nscl[64], nshl[64];
    // total LDS = 32768 + 4608 + 1536 = 38912 B -> 4 blocks/CU

    const int tid  = threadIdx.x;
    const int lane = tid & 63;
    const int wid  = tid >> 6;
    const int cl   = lane & 15;
    const int pg   = lane >> 4;

    // bijective XCD swizzle: 800 = 8 * 100
    const int bid0 = blockIdx.x;
    const int bid  = (bid0 & 7) * 100 + (bid0 >> 3);
    const int n    = bid / 200;
    const int rem  = bid - n * 200;
    const int ht   = rem / 5;
    const int wt   = rem - ht * 5;
    const int h    = ht * 4;
    const int w0   = wt * 32;

    const float* ybase = y + (size_t)n * (64 * HH * WW);
    const float* xbase = x + (size_t)n * (64 * HH * WW);

    for (int e = tid; e < 576; e += 256) { dwl[e] = dw0[e]; dwl[576 + e] = dw1[e]; }
    if (tid < 64) {
        float s0 = g0[tid] * rsqrtf(v0[tid] + 1e-5f);
        scb[tid] = s0;      shb[tid] = bb0[tid] - m0[tid] * s0;
        float s1 = g1[tid] * rsqrtf(v1[tid] + 1e-5f);
        scb[64 + tid] = s1; shb[64 + tid] = bb1[tid] - m1[tid] * s1;
        float sn = ng[tid] * rsqrtf(nv[tid] + 1e-5f);
        nscl[tid] = sn;     nshl[tid] = nbb[tid] - nm[tid] * sn;
    }
    __syncthreads();

    float outacc[2][4][4];   // [mt][ct][rr] - all indices static everywhere
    #pragma unroll
    for (int mt = 0; mt < 2; ++mt)
        #pragma unroll
        for (int ct = 0; ct < 4; ++ct)
            #pragma unroll
            for (int rr = 0; rr < 4; ++rr) outacc[mt][ct][rr] = 0.f;

    #pragma unroll 1
    for (int b = 0; b < 2; ++b) {
        const int r = b + 1;
        if (b) __syncthreads();   // all waves done with afr reads of prev branch

        // ---- depthwise conv + BN + ReLU -> t (bf16 hi/lo, swizzled) ------
        {
            const int px = tid & 127;
            const int rl = px >> 5, wl = px & 31;
            const int cb = (tid >> 7) * 4;
            #pragma unroll 1
            for (int it = 0; it < 4; ++it) {
                const int chunk = cb + it;           // 0..7
                const int cp0 = chunk * 8;
                bf16x8 h8, l8;
                #pragma unroll
                for (int jc = 0; jc < 8; ++jc) {
                    const int cp = cp0 + jc;
                    float a = 0.f;
                    #pragma unroll
                    for (int i = 0; i < 3; ++i) {
                        const int hr = h + rl + (i - 1) * r;
                        const bool hok = (unsigned)hr < (unsigned)HH;
                        const float* yr = ybase + ((size_t)cp * HH + hr) * WW;
                        #pragma unroll
                        for (int j = 0; j < 3; ++j) {
                            const int wc = w0 + wl + (j - 1) * r;
                            float yv = (hok && (unsigned)wc < (unsigned)WW) ? yr[wc] : 0.f;
                            a = fmaf(yv, dwl[b * 576 + cp * 9 + i * 3 + j], a);
                        }
                    }
                    float tv = fmaxf(fmaf(a, scb[b * 64 + cp], shb[b * 64 + cp]), 0.f);
                    unsigned short hb = f32_to_bf16_rne(tv);
                    h8[jc] = (short)hb;
                    l8[jc] = (short)f32_to_bf16_rne(tv - bf16_to_f32(hb));
                }
                const int phys = chunk ^ ((px >> 1) & 7);
                *(bf16x8*)&t_hi[px * 64 + phys * 8] = h8;
                *(bf16x8*)&t_lo[px * 64 + phys * 8] = l8;
            }
        }
        __syncthreads();

        // ---- A fragments: 32 px (2 M-frags), K=64, hi+lo (32 VGPRs) ------
        bf16x8 afr0[2][2], afr1[2][2];   // [kh][comp], named per M-frag
        #pragma unroll
        for (int kh = 0; kh < 2; ++kh) {
            {
                const int px = wid * 32 + cl;
                const int phys = (kh * 4 + pg) ^ ((px >> 1) & 7);
                afr0[kh][0] = *(const bf16x8*)&t_hi[px * 64 + phys * 8];
                afr0[kh][1] = *(const bf16x8*)&t_lo[px * 64 + phys * 8];
            }
            {
                const int px = wid * 32 + 16 + cl;
                const int phys = (kh * 4 + pg) ^ ((px >> 1) & 7);
                afr1[kh][0] = *(const bf16x8*)&t_hi[px * 64 + phys * 8];
                afr1[kh][1] = *(const bf16x8*)&t_lo[px * 64 + phys * 8];
            }
        }

        // ---- GEMM + unfold contraction: runtime kk-loop, ct unrolled -----
        const unsigned short* wfB = wF + (size_t)b * 9 * 16 * 512;
        const float* pwbg = b ? pwb1 : pwb0;
        const int xrow_base = h + wid;

        #pragma unroll 1
        for (int kk = 0; kk < 9; ++kk) {
            const int di = (kk >= 6) ? 2 : ((kk >= 3) ? 1 : 0);
            const int dj = kk - di * 3;
            const int xrow = xrow_base + (di - 1) * r;
            const bool rowok = (unsigned)xrow < (unsigned)HH;
            const unsigned short* wfk = wfB + (size_t)kk * 16 * 512;
            const int xcb = w0 + pg * 4 + (dj - 1) * r;

            #pragma unroll
            for (int ct = 0; ct < 4; ++ct) {
                // B fragments (L2-resident), issued first
                bf16x8 bfr[2][2];
                #pragma unroll
                for (int kh = 0; kh < 2; ++kh)
                    #pragma unroll
                    for (int cm = 0; cm < 2; ++cm)
                        bfr[kh][cm] = *(const bf16x8*)&wfk[(ct * 4 + kh * 2 + cm) * 512 + lane * 8];

                const int c = ct * 16 + cl;
                // x loads issued before MFMAs (latency hidden under MFMA)
                const float* xrp = xbase + ((size_t)c * HH + xrow) * WW;
                f32x4 xv0, xv1;
                {
                    const int xc0 = xcb;
                    if (rowok && (unsigned)xc0 <= (unsigned)(WW - 4)) {
                        __builtin_memcpy(&xv0, xrp + xc0, 16);
                    } else {
                        #pragma unroll
                        for (int rr = 0; rr < 4; ++rr) {
                            const int xc = xc0 + rr;
                            xv0[rr] = (rowok && (unsigned)xc < (unsigned)WW) ? xrp[xc] : 0.f;
                        }
                    }
                    const int xc1 = xcb + 16;
                    if (rowok && (unsigned)xc1 <= (unsigned)(WW - 4)) {
                        __builtin_memcpy(&xv1, xrp + xc1, 16);
                    } else {
                        #pragma unroll
                        for (int rr = 0; rr < 4; ++rr) {
                            const int xc = xc1 + rr;
                            xv1[rr] = (rowok && (unsigned)xc < (unsigned)WW) ? xrp[xc] : 0.f;
                        }
                    }
                }
                const float bv = pwbg[c * 9 + kk];
                f32x4 k0 = {bv, bv, bv, bv};
                f32x4 k1 = k0;
                // bf16x3: hi*hi + hi*lo + lo*hi
                #pragma unroll
                for (int p = 0; p < 3; ++p) {
                    const int ac = (p == 2) ? 1 : 0;
                    const int bc = (p == 1) ? 1 : 0;
                    #pragma unroll
                    for (int kh = 0; kh < 2; ++kh) {
                        k0 = __builtin_amdgcn_mfma_f32_16x16x32_bf16(
                            afr0[kh][ac], bfr[kh][bc], k0, 0, 0, 0);
                        k1 = __builtin_amdgcn_mfma_f32_16x16x32_bf16(
                            afr1[kh][ac], bfr[kh][bc], k1, 0, 0, 0);
                    }
                }
                #pragma unroll
                for (int rr = 0; rr < 4; ++rr) {
                    outacc[0][ct][rr] = fmaf(k0[rr], xv0[rr], outacc[0][ct][rr]);
                    outacc[1][ct][rr] = fmaf(k1[rr], xv1[rr], outacc[1][ct][rr]);
                }
            }
        }
    }

    // ---- epilogue: final BN + ReLU, coalesced float4 stores --------------
    {
        const int hrow = h + wid;
        #pragma unroll
        for (int mt = 0; mt < 2; ++mt) {
            const int wc0 = w0 + mt * 16 + pg * 4;
            #pragma unroll
            for (int ct = 0; ct < 4; ++ct) {
                const int c = ct * 16 + cl;
                const float sn = nscl[c], sh = nshl[c];
                f32x4 o;
                #pragma unroll
                for (int rr = 0; rr < 4; ++rr)
                    o[rr] = fmaxf(fmaf(outacc[mt][ct][rr], sn, sh), 0.f);
                *(f32x4*)&out[(((size_t)n * 64 + c) * HH + hrow) * WW + wc0] = o;
            }
        }
    }
}

extern "C" void kernel_launch(void* const* d_in, const int* in_sizes, int n_in,
                              void* d_out, int out_size, void* d_ws, size_t ws_size,
                              hipStream_t stream) {
    const float* y    = (const float*)d_in[0];
    const float* x    = (const float*)d_in[1];
    const float* dw0  = (const float*)d_in[2];
    const float* g0   = (const float*)d_in[3];
    const float* b0   = (const float*)d_in[4];
    const float* m0   = (const float*)d_in[5];
    const float* v0   = (const float*)d_in[6];
    const float* pw0  = (const float*)d_in[7];
    const float* pwb0 = (const float*)d_in[8];
    const float* dw1  = (const float*)d_in[9];
    const float* g1   = (const float*)d_in[10];
    const float* b1   = (const float*)d_in[11];
    const float* m1   = (const float*)d_in[12];
    const float* v1   = (const float*)d_in[13];
    const float* pw1  = (const float*)d_in[14];
    const float* pwb1 = (const float*)d_in[15];
    const float* ng   = (const float*)d_in[16];
    const float* nb   = (const float*)d_in[17];
    const float* nm   = (const float*)d_in[18];
    const float* nv   = (const float*)d_in[19];

    unsigned short* wF = (unsigned short*)d_ws;   // 294912 B

    prep_w_kernel<<<72, 256, 0, stream>>>(pw0, pw1, wF);
    fused_kernel<<<800, 256, 0, stream>>>(y, x,
                                          dw0, g0, b0, m0, v0, pwb0,
                                          dw1, g1, b1, m1, v1, pwb1,
                                          ng, nb, nm, nv, wF, (float*)d_out);
}

// Round 8
// 270.164 us; speedup vs baseline: 2.1318x; 2.1318x over previous
//
#include <hip/hip_runtime.h>

#define HH 160
#define WW 160

typedef __attribute__((ext_vector_type(8))) short bf16x8;
typedef __attribute__((ext_vector_type(4))) float f32x4;

static __device__ __forceinline__ unsigned short f32_to_bf16_rne(float f) {
    unsigned u = __float_as_uint(f);
    unsigned r = (u + 0x7FFFu + ((u >> 16) & 1u)) >> 16;
    return (unsigned short)r;
}
static __device__ __forceinline__ float bf16_to_f32(unsigned short h) {
    return __uint_as_float(((unsigned)h) << 16);
}

// async global->LDS, 16B per lane. g includes lane*16; lbase is wave-uniform.
static __device__ __forceinline__ void stage16(const char* g, char* lbase, int lane) {
#if __has_builtin(__builtin_amdgcn_global_load_lds)
    __builtin_amdgcn_global_load_lds(
        (const __attribute__((address_space(1))) unsigned int*)g,
        (__attribute__((address_space(3))) unsigned int*)lbase, 16, 0, 0);
#else
    *(f32x4*)(lbase + lane * 16) = *(const f32x4*)g;
#endif
}

// ---------------------------------------------------------------------------
// Prep: pack pw_w[2] into MFMA B-fragment layout, bf16 hi/lo split.
// tile tn = b*9+kk (16 KB each); frag-in-tile = ct*4 + kh*2 + comp (1 KB each).
// Element (lane,j): B[k=kh*32+(lane>>4)*8+j][n=ct*16+(lane&15)], W[cp][c]=pw[(c*9+kk)*64+cp]
// ---------------------------------------------------------------------------
__global__ __launch_bounds__(256) void prep_w_kernel(const float* __restrict__ pw0,
                                                     const float* __restrict__ pw1,
                                                     unsigned short* __restrict__ wF) {
    int idx = blockIdx.x * 256 + threadIdx.x;   // 288*64 = 18432
    if (idx >= 18432) return;
    int lane = idx & 63;
    int frag = idx >> 6;
    int comp = frag & 1;
    int kh   = (frag >> 1) & 1;
    int ct   = (frag >> 2) & 3;
    int t    = frag >> 4;             // b*9+kk
    int bb   = t / 9;
    int kk   = t - bb * 9;
    const float* pw = bb ? pw1 : pw0;
    int c = ct * 16 + (lane & 15);
    bf16x8 pack;
    #pragma unroll
    for (int j = 0; j < 8; ++j) {
        int cp = kh * 32 + (lane >> 4) * 8 + j;
        float v = pw[(c * 9 + kk) * 64 + cp];
        unsigned short hb = f32_to_bf16_rne(v);
        if (comp == 0) pack[j] = (short)hb;
        else           pack[j] = (short)f32_to_bf16_rne(v - bf16_to_f32(hb));
    }
    *(bf16x8*)&wF[frag * 512 + lane * 8] = pack;
}

// ---------------------------------------------------------------------------
// Fused kernel. Block = 4 h-rows x 32 w = 128 px, 4 waves; wave owns one row
// (2 M-frags) x all 64 output channels. B tiles (16 KB/kk) double-buffered in
// LDS via async global_load_lds (T3 2-phase); one barrier per kk. x read as
// aligned f32x4 register windows per di, statically indexed. Zero scratch.
// ---------------------------------------------------------------------------
__global__ __launch_bounds__(256, 2) void fused_kernel(
    const float* __restrict__ y,   const float* __restrict__ x,
    const float* __restrict__ dw0, const float* __restrict__ g0,
    const float* __restrict__ bb0, const float* __restrict__ m0,
    const float* __restrict__ v0,  const float* __restrict__ pwb0,
    const float* __restrict__ dw1, const float* __restrict__ g1,
    const float* __restrict__ bb1, const float* __restrict__ m1,
    const float* __restrict__ v1,  const float* __restrict__ pwb1,
    const float* __restrict__ ng,  const float* __restrict__ nbb,
    const float* __restrict__ nm,  const float* __restrict__ nv,
    const unsigned short* __restrict__ wF, float* __restrict__ out)
{
    __shared__ unsigned short t_hi[128 * 64];        // 16 KB, XOR-swizzled
    __shared__ unsigned short t_lo[128 * 64];        // 16 KB
    __shared__ __align__(16) char bbuf[2 * 16384];   // 32 KB B double-buffer
    __shared__ float dwl[2 * 576];                   // 4.5 KB
    __shared__ float pwbl[2 * 576];                  // 4.5 KB
    __shared__ float scb[2 * 64], shb[2 * 64], nscl[64], nshl[64];
    // total ~74.5 KB -> 2 blocks/CU

    const int tid  = threadIdx.x;
    const int lane = tid & 63;
    const int wid  = tid >> 6;
    const int cl   = lane & 15;
    const int pg   = lane >> 4;

    // bijective XCD swizzle: 800 = 8 * 100
    const int bid0 = blockIdx.x;
    const int bid  = (bid0 & 7) * 100 + (bid0 >> 3);
    const int n    = bid / 200;
    const int rem  = bid - n * 200;
    const int ht   = rem / 5;
    const int wt   = rem - ht * 5;
    const int h    = ht * 4;
    const int w0   = wt * 32;

    const float* ybase = y + (size_t)n * (64 * HH * WW);
    const float* xbase = x + (size_t)n * (64 * HH * WW);
    const char*  wfb8  = (const char*)wF;
    char*        bb    = bbuf;

    for (int e = tid; e < 576; e += 256) {
        dwl[e] = dw0[e];  dwl[576 + e] = dw1[e];
        pwbl[e] = pwb0[e]; pwbl[576 + e] = pwb1[e];
    }
    if (tid < 64) {
        float s0 = g0[tid] * rsqrtf(v0[tid] + 1e-5f);
        scb[tid] = s0;      shb[tid] = bb0[tid] - m0[tid] * s0;
        float s1 = g1[tid] * rsqrtf(v1[tid] + 1e-5f);
        scb[64 + tid] = s1; shb[64 + tid] = bb1[tid] - m1[tid] * s1;
        float sn = ng[tid] * rsqrtf(nv[tid] + 1e-5f);
        nscl[tid] = sn;     nshl[tid] = nbb[tid] - nm[tid] * sn;
    }
    // stage B tile 0 (async; drained by the syncthreads below)
    #pragma unroll
    for (int it = 0; it < 4; ++it)
        stage16(wfb8 + ((wid + it * 4) << 10) + lane * 16,
                bb + ((wid + it * 4) << 10), lane);
    __syncthreads();

    float outacc[2][4][4];   // [mt][ct][rr] - static indices only
    #pragma unroll
    for (int mt = 0; mt < 2; ++mt)
        #pragma unroll
        for (int ct = 0; ct < 4; ++ct)
            #pragma unroll
            for (int rr = 0; rr < 4; ++rr) outacc[mt][ct][rr] = 0.f;

    #pragma unroll
    for (int b = 0; b < 2; ++b) {
        const int r = b + 1;
        if (b) __syncthreads();   // protect t overwrite (all waves past b=0 compute)

        // ---- depthwise conv + BN + ReLU -> t (bf16 hi/lo, swizzled) ------
        {
            const int px = tid & 127;
            const int rl = px >> 5, wl = px & 31;
            const int cb = (tid >> 7) * 4;
            #pragma unroll 1
            for (int it = 0; it < 4; ++it) {
                const int chunk = cb + it;           // 0..7
                const int cp0 = chunk * 8;
                bf16x8 h8, l8;
                #pragma unroll
                for (int jc = 0; jc < 8; ++jc) {
                    const int cp = cp0 + jc;
                    float a = 0.f;
                    #pragma unroll
                    for (int i = 0; i < 3; ++i) {
                        const int hr = h + rl + (i - 1) * r;
                        const bool hok = (unsigned)hr < (unsigned)HH;
                        const float* yr = ybase + ((size_t)cp * HH + hr) * WW;
                        #pragma unroll
                        for (int j = 0; j < 3; ++j) {
                            const int wc = w0 + wl + (j - 1) * r;
                            float yv = (hok && (unsigned)wc < (unsigned)WW) ? yr[wc] : 0.f;
                            a = fmaf(yv, dwl[b * 576 + cp * 9 + i * 3 + j], a);
                        }
                    }
                    float tv = fmaxf(fmaf(a, scb[b * 64 + cp], shb[b * 64 + cp]), 0.f);
                    unsigned short hb = f32_to_bf16_rne(tv);
                    h8[jc] = (short)hb;
                    l8[jc] = (short)f32_to_bf16_rne(tv - bf16_to_f32(hb));
                }
                const int phys = chunk ^ ((px >> 1) & 7);
                *(bf16x8*)&t_hi[px * 64 + phys * 8] = h8;
                *(bf16x8*)&t_lo[px * 64 + phys * 8] = l8;
            }
        }
        __syncthreads();

        // ---- A fragments: 32 px (2 M-frags), K=64, hi+lo (32 VGPRs) ------
        bf16x8 afr0[2][2], afr1[2][2];   // [kh][comp]
        #pragma unroll
        for (int kh = 0; kh < 2; ++kh) {
            {
                const int px = wid * 32 + cl;
                const int phys = (kh * 4 + pg) ^ ((px >> 1) & 7);
                afr0[kh][0] = *(const bf16x8*)&t_hi[px * 64 + phys * 8];
                afr0[kh][1] = *(const bf16x8*)&t_lo[px * 64 + phys * 8];
            }
            {
                const int px = wid * 32 + 16 + cl;
                const int phys = (kh * 4 + pg) ^ ((px >> 1) & 7);
                afr1[kh][0] = *(const bf16x8*)&t_hi[px * 64 + phys * 8];
                afr1[kh][1] = *(const bf16x8*)&t_lo[px * 64 + phys * 8];
            }
        }

        // ---- kk loop: 2-phase B dbuf + register x windows ----------------
        #pragma unroll 1
        for (int di = 0; di < 3; ++di) {
            const int xrow = h + wid + (di - 1) * r;
            const bool rowok = (unsigned)xrow < (unsigned)HH;

            float win[4][2][12];   // static indices only
            #pragma unroll
            for (int ct = 0; ct < 4; ++ct) {
                const int c = ct * 16 + cl;
                const float* xrp = xbase + ((size_t)c * HH + xrow) * WW;
                #pragma unroll
                for (int mt = 0; mt < 2; ++mt) {
                    const int pgb = w0 + mt * 16 + pg * 4;
                    #pragma unroll
                    for (int q = 0; q < 3; ++q) {
                        const int col = pgb - 4 + q * 4;
                        f32x4 v = {0.f, 0.f, 0.f, 0.f};
                        // cols are multiples of 4; WW=160 -> chunks fully in or out
                        if (rowok && col >= 0 && col <= (WW - 4))
                            v = *(const f32x4*)(xrp + col);
                        win[ct][mt][q * 4 + 0] = v[0];
                        win[ct][mt][q * 4 + 1] = v[1];
                        win[ct][mt][q * 4 + 2] = v[2];
                        win[ct][mt][q * 4 + 3] = v[3];
                    }
                }
            }

            #pragma unroll
            for (int dj = 0; dj < 3; ++dj) {
                const int kk  = 3 * di + dj;
                const int tn  = b * 9 + kk;
                const int par = tn & 1;
                const char* bcur = bb + (par << 14);
                char*       bnxt = bb + ((par ^ 1) << 14);

                // stage next B tile (flows during MFMAs, drained at barrier)
                if (tn < 17) {
                    const char* s = wfb8 + ((size_t)(tn + 1) << 14);
                    #pragma unroll
                    for (int it = 0; it < 4; ++it)
                        stage16(s + ((wid + it * 4) << 10) + lane * 16,
                                bnxt + ((wid + it * 4) << 10), lane);
                }

                #pragma unroll
                for (int ct = 0; ct < 4; ++ct) {
                    bf16x8 bfr[2][2];
                    #pragma unroll
                    for (int kh = 0; kh < 2; ++kh)
                        #pragma unroll
                        for (int cm = 0; cm < 2; ++cm)
                            bfr[kh][cm] = *(const bf16x8*)(bcur +
                                ((ct * 4 + kh * 2 + cm) << 10) + lane * 16);

                    const int c = ct * 16 + cl;
                    const float bv = pwbl[b * 576 + c * 9 + kk];
                    f32x4 k0 = {bv, bv, bv, bv};
                    f32x4 k1 = k0;
                    // bf16x3: hi*hi + hi*lo + lo*hi
                    #pragma unroll
                    for (int p = 0; p < 3; ++p) {
                        const int ac = (p == 2) ? 1 : 0;
                        const int bc = (p == 1) ? 1 : 0;
                        #pragma unroll
                        for (int kh = 0; kh < 2; ++kh) {
                            k0 = __builtin_amdgcn_mfma_f32_16x16x32_bf16(
                                afr0[kh][ac], bfr[kh][bc], k0, 0, 0, 0);
                            k1 = __builtin_amdgcn_mfma_f32_16x16x32_bf16(
                                afr1[kh][ac], bfr[kh][bc], k1, 0, 0, 0);
                        }
                    }
                    #pragma unroll
                    for (int rr = 0; rr < 4; ++rr) {
                        outacc[0][ct][rr] = fmaf(k0[rr], win[ct][0][4 + (dj - 1) * r + rr],
                                                 outacc[0][ct][rr]);
                        outacc[1][ct][rr] = fmaf(k1[rr], win[ct][1][4 + (dj - 1) * r + rr],
                                                 outacc[1][ct][rr]);
                    }
                }
                __syncthreads();   // drains stage; next tile ready, bcur consumed
            }
        }
    }

    // ---- epilogue: final BN + ReLU, coalesced float4 stores --------------
    {
        const int hrow = h + wid;
        #pragma unroll
        for (int mt = 0; mt < 2; ++mt) {
            const int wc0 = w0 + mt * 16 + pg * 4;
            #pragma unroll
            for (int ct = 0; ct < 4; ++ct) {
                const int c = ct * 16 + cl;
                const float sn = nscl[c], sh = nshl[c];
                f32x4 o;
                #pragma unroll
                for (int rr = 0; rr < 4; ++rr)
                    o[rr] = fmaxf(fmaf(outacc[mt][ct][rr], sn, sh), 0.f);
                *(f32x4*)&out[(((size_t)n * 64 + c) * HH + hrow) * WW + wc0] = o;
            }
        }
    }
}

extern "C" void kernel_launch(void* const* d_in, const int* in_sizes, int n_in,
                              void* d_out, int out_size, void* d_ws, size_t ws_size,
                              hipStream_t stream) {
    const float* y    = (const float*)d_in[0];
    const float* x    = (const float*)d_in[1];
    const float* dw0  = (const float*)d_in[2];
    const float* g0   = (const float*)d_in[3];
    const float* b0   = (const float*)d_in[4];
    const float* m0   = (const float*)d_in[5];
    const float* v0   = (const float*)d_in[6];
    const float* pw0  = (const float*)d_in[7];
    const float* pwb0 = (const float*)d_in[8];
    const float* dw1  = (const float*)d_in[9];
    const float* g1   = (const float*)d_in[10];
    const float* b1   = (const float*)d_in[11];
    const float* m1   = (const float*)d_in[12];
    const float* v1   = (const float*)d_in[13];
    const float* pw1  = (const float*)d_in[14];
    const float* pwb1 = (const float*)d_in[15];
    const float* ng   = (const float*)d_in[16];
    const float* nb   = (const float*)d_in[17];
    const float* nm   = (const float*)d_in[18];
    const float* nv   = (const float*)d_in[19];

    unsigned short* wF = (unsigned short*)d_ws;   // 294912 B

    prep_w_kernel<<<72, 256, 0, stream>>>(pw0, pw1, wF);
    fused_kernel<<<800, 256, 0, stream>>>(y, x,
                                          dw0, g0, b0, m0, v0, pwb0,
                                          dw1, g1, b1, m1, v1, pwb1,
                                          ng, nb, nm, nv, wF, (float*)d_out);
}